// Round 3
// baseline (125519.055 us; speedup 1.0000x reference)
//
#include <hip/hip_runtime.h>
#include <hip/hip_bf16.h>

#define NS 32768
#define NT 512
#define HD 64

// d_ws layout (floats):
//   0      f-net weights, ORIGINAL tensor order (8900) + 4 pad
//   8904   g-net weights (8900) + 4 pad        <- stride 8904 == 8 (mod 32):
//          f/g LDS copies land on disjoint bank quads -> weight reads 2-way max
//   17808  dts[511]
//   18319  sqdts[511]
//   18830  flag (1.0 if bf16 inputs else 0.0)
// Within-net offsets: W1 0(256) b1 256(64) W2 320(4096) b2 4416(64)
//                     W3 4480(4096) b3 8576(64) W4 8640(256) b4 8896(4)
#define WS_NETSTRIDE 8904
#define WS_DTS 17808
#define WS_SQ 18319
#define WS_FLAG 18830

typedef float v2f __attribute__((ext_vector_type(2)));
typedef float v4f __attribute__((ext_vector_type(4)));

struct P16 { const void* p[16]; };

__global__ void prep_kernel(P16 wp, const void* timesp, float* ws) {
  const int offs[9] = {0, 256, 320, 4416, 4480, 8576, 8640, 8896, 8900};
  unsigned first = ((const unsigned*)timesp)[0];
  bool isbf = (first != 0u);  // times[0]==0.0f -> fp32 dword is 0; bf16 pair is 0x3C240000
  int tid = blockIdx.x * blockDim.x + threadIdx.x;
  int stride = gridDim.x * blockDim.x;
  for (int idx = tid; idx < WS_DTS + (NT - 1); idx += stride) {
    if (idx < WS_DTS) {
      int net = (idx >= WS_NETSTRIDE) ? 1 : 0;
      int r = idx - net * WS_NETSTRIDE;
      if (r >= 8900) { ws[idx] = 0.0f; continue; }  // pad
      int ti = 0;
      while (r >= offs[ti + 1]) ti++;
      int src = r - offs[ti];
      ti += net * 8;
      float v = isbf ? __bfloat162float(((const __hip_bfloat16*)wp.p[ti])[src])
                     : ((const float*)wp.p[ti])[src];
      ws[idx] = v;
    } else {
      int t = idx - WS_DTS;
      float t0, t1;
      if (isbf) {
        t0 = __bfloat162float(((const __hip_bfloat16*)timesp)[t]);
        t1 = __bfloat162float(((const __hip_bfloat16*)timesp)[t + 1]);
      } else {
        t0 = ((const float*)timesp)[t];
        t1 = ((const float*)timesp)[t + 1];
      }
      float dt = t1 - t0;
      ws[WS_DTS + t] = dt;
      ws[WS_SQ + t] = sqrtf(dt);
    }
  }
  if (blockIdx.x == 0 && threadIdx.x == 0) ws[WS_FLAG] = isbf ? 1.0f : 0.0f;
}

__device__ __forceinline__ float lipswish(float x) {
  float e = __expf(-x);
  return 0.909f * x * __builtin_amdgcn_rcpf(1.0f + e);
}

__device__ __forceinline__ unsigned short f2bs(float x) {
  return __bfloat16_as_ushort(__float2bfloat16(x));
}

__device__ __forceinline__ void store_out(void* outp, bool isbf, int sample, int t,
                                          const float v[4]) {
  if (isbf) {
    uint2 u;
    u.x = (unsigned)f2bs(v[0]) | ((unsigned)f2bs(v[1]) << 16);
    u.y = (unsigned)f2bs(v[2]) | ((unsigned)f2bs(v[3]) << 16);
    ((uint2*)outp)[(size_t)sample * NT + t] = u;
  } else {
    float4 f = make_float4(v[0], v[1], v[2], v[3]);
    ((float4*)outp)[(size_t)sample * NT + t] = f;
  }
}

#define HA(idx) ha[(idx) >> 1][(idx) & 1]
#define HB(idx) hb[(idx) >> 1][(idx) & 1]

// block = 512 threads = 8 waves = 64 samples; 8 lanes per sample:
//   lane bits [2:0] = member: net = bit2 (0=f,1=g), slab = bits[1:0] (16 units).
// Each lane computes 16 hidden units for ONE sample. Hidden exchange between
// layers is IN-WAVE via ds_bpermute (source lane = same sample/net, slab=k>>4).
// L4 partials reduced via shfl_xor butterfly (same pairwise tree as before ->
// bit-identical), f/g mixed via shfl_xor(.,4). All weights + dts staged once
// into LDS -> zero SMEM and ZERO BARRIERS in the time loop; waves fully
// independent. Inner products use v2f + elementwise_fma -> v_pk_fma_f32.
// LDS 75.3KB -> 2 blocks/CU = 16 waves/CU = 4 waves/SIMD.
__global__ __launch_bounds__(512, 4) void sde_kernel(
    const void* __restrict__ y0p, const void* __restrict__ noisep,
    const float* __restrict__ ws, void* __restrict__ outp) {
  const int tid = threadIdx.x;
  const int lane = tid & 63;
  const int slab = tid & 3;
  const int net = (tid >> 2) & 1;
  const int sample = blockIdx.x * 64 + (tid >> 3);
  const bool isbf = (ws[WS_FLAG] != 0.0f);

  __shared__ float lw[18830];  // weights(17808) + {dt,sqdt} pairs (1022)
  {
    const float4* s4 = (const float4*)ws;
    float4* d4 = (float4*)lw;
    for (int i = tid; i < (2 * WS_NETSTRIDE) / 4; i += 512) d4[i] = s4[i];
    if (tid < NT - 1) {
      lw[17808 + 2 * tid] = ws[WS_DTS + tid];
      lw[17808 + 2 * tid + 1] = ws[WS_SQ + tid];
    }
  }
  __syncthreads();  // the only barrier in the kernel

  const int nb = net * WS_NETSTRIDE;
  const float* w1 = lw + nb + slab * 16;           // + k*64, k<4
  const float* bb1 = lw + nb + 256 + slab * 16;
  const float* w2 = lw + nb + 320 + slab * 16;     // + k*64
  const float* bb2 = lw + nb + 4416 + slab * 16;
  const float* w3 = lw + nb + 4480 + slab * 16;    // + k*64
  const float* bb3 = lw + nb + 8576 + slab * 16;
  const float* w4 = lw + nb + 8640 + slab * 64;    // + kk*4
  const float* b4p = lw + nb + 8896;

  const int pbase = (lane & ~3) << 2;  // bpermute byte addr base (slab bits cleared)

  v4f b4v = *(const v4f*)b4p;
  const v2f b4A = (slab == 0) ? (v2f){b4v.x, b4v.y} : (v2f){0.f, 0.f};
  const v2f b4B = (slab == 0) ? (v2f){b4v.z, b4v.w} : (v2f){0.f, 0.f};

  float y[4];
  if (isbf) {
    uint2 u = ((const uint2*)y0p)[sample];
    y[0] = __uint_as_float((u.x & 0xffffu) << 16);
    y[1] = __uint_as_float(u.x & 0xffff0000u);
    y[2] = __uint_as_float((u.y & 0xffffu) << 16);
    y[3] = __uint_as_float(u.y & 0xffff0000u);
  } else {
    float4 f = ((const float4*)y0p)[sample];
    y[0] = f.x; y[1] = f.y; y[2] = f.z; y[3] = f.w;
  }

  if ((tid & 7) == 0) store_out(outp, isbf, sample, 0, y);

  for (int t = 0; t < NT - 1; ++t) {
    // prefetch this step's noise early; used only at the end of the step
    float dw[4];
    if (isbf) {
      uint2 nz = ((const uint2*)noisep)[(size_t)t * NS + sample];
      dw[0] = __uint_as_float((nz.x & 0xffffu) << 16);
      dw[1] = __uint_as_float(nz.x & 0xffff0000u);
      dw[2] = __uint_as_float((nz.y & 0xffffu) << 16);
      dw[3] = __uint_as_float(nz.y & 0xffff0000u);
    } else {
      float4 nz = ((const float4*)noisep)[(size_t)t * NS + sample];
      dw[0] = nz.x; dw[1] = nz.y; dw[2] = nz.z; dw[3] = nz.w;
    }

    v2f ha[8], hb[8];
    // L1: y[4] -> 16 units of this lane's slab
#pragma unroll
    for (int c = 0; c < 4; ++c) {
      v4f b = *(const v4f*)(bb1 + 4 * c);
      ha[2 * c] = (v2f){b.x, b.y};
      ha[2 * c + 1] = (v2f){b.z, b.w};
    }
#pragma unroll
    for (int k = 0; k < 4; ++k) {
      v2f yk = (v2f){y[k], y[k]};
#pragma unroll
      for (int c = 0; c < 4; ++c) {
        v4f w = *(const v4f*)(w1 + k * 64 + 4 * c);
        ha[2 * c] = __builtin_elementwise_fma(yk, (v2f){w.x, w.y}, ha[2 * c]);
        ha[2 * c + 1] = __builtin_elementwise_fma(yk, (v2f){w.z, w.w}, ha[2 * c + 1]);
      }
    }
#pragma unroll
    for (int j = 0; j < 8; ++j) {
      ha[j][0] = lipswish(ha[j][0]);
      ha[j][1] = lipswish(ha[j][1]);
    }

    // L2: gather h1[k] of MY sample/net via bpermute, accumulate 16 units
#pragma unroll
    for (int c = 0; c < 4; ++c) {
      v4f b = *(const v4f*)(bb2 + 4 * c);
      hb[2 * c] = (v2f){b.x, b.y};
      hb[2 * c + 1] = (v2f){b.z, b.w};
    }
#pragma unroll
    for (int k = 0; k < HD; ++k) {
      float hk = __int_as_float(__builtin_amdgcn_ds_bpermute(
          pbase + ((k >> 4) << 2), __float_as_int(HA(k & 15))));
      v2f hk2 = (v2f){hk, hk};
#pragma unroll
      for (int c = 0; c < 4; ++c) {
        v4f w = *(const v4f*)(w2 + k * 64 + 4 * c);
        hb[2 * c] = __builtin_elementwise_fma(hk2, (v2f){w.x, w.y}, hb[2 * c]);
        hb[2 * c + 1] = __builtin_elementwise_fma(hk2, (v2f){w.z, w.w}, hb[2 * c + 1]);
      }
    }
#pragma unroll
    for (int j = 0; j < 8; ++j) {
      hb[j][0] = lipswish(hb[j][0]);
      hb[j][1] = lipswish(hb[j][1]);
    }

    // L3: same, hb -> ha (pre-acts kept in regs)
#pragma unroll
    for (int c = 0; c < 4; ++c) {
      v4f b = *(const v4f*)(bb3 + 4 * c);
      ha[2 * c] = (v2f){b.x, b.y};
      ha[2 * c + 1] = (v2f){b.z, b.w};
    }
#pragma unroll
    for (int k = 0; k < HD; ++k) {
      float hk = __int_as_float(__builtin_amdgcn_ds_bpermute(
          pbase + ((k >> 4) << 2), __float_as_int(HB(k & 15))));
      v2f hk2 = (v2f){hk, hk};
#pragma unroll
      for (int c = 0; c < 4; ++c) {
        v4f w = *(const v4f*)(w3 + k * 64 + 4 * c);
        ha[2 * c] = __builtin_elementwise_fma(hk2, (v2f){w.x, w.y}, ha[2 * c]);
        ha[2 * c + 1] = __builtin_elementwise_fma(hk2, (v2f){w.z, w.w}, ha[2 * c + 1]);
      }
    }

    // L4: this lane's 16 h3 -> partial o[4] (k-split over slabs)
    v2f oA = b4A, oB = b4B;
#pragma unroll
    for (int kk = 0; kk < 16; ++kk) {
      float h3 = lipswish(HA(kk));
      v4f w = *(const v4f*)(w4 + kk * 4);
      v2f h2 = (v2f){h3, h3};
      oA = __builtin_elementwise_fma(h2, (v2f){w.x, w.y}, oA);
      oB = __builtin_elementwise_fma(h2, (v2f){w.z, w.w}, oB);
    }
    float o[4] = {oA[0], oA[1], oB[0], oB[1]};

    // reduce over slabs (same pairwise tree as before -> bit-identical)
#pragma unroll
    for (int d = 0; d < 4; ++d) {
      o[d] += __shfl_xor(o[d], 1);
      o[d] += __shfl_xor(o[d], 2);
    }

    // f/g exchange + Euler-Maruyama update (redundant across the 8 member lanes)
    const v2f dt2 = *(const v2f*)(lw + 17808 + 2 * t);  // {dt, sqdt}
#pragma unroll
    for (int d = 0; d < 4; ++d) {
      float oo = __shfl_xor(o[d], 4);
      float fo = net ? oo : o[d];
      float go = net ? o[d] : oo;
      float drift = fminf(fmaxf(fo, -100.0f), 100.0f);
      float sp = fmaxf(go, 0.0f) + log1pf(__expf(-fabsf(go)));  // stable softplus
      float diff = fmaxf(sp, 1e-4f);
      y[d] = y[d] + drift * dt2[0] + diff * dt2[1] * dw[d];
    }

    if ((tid & 7) == 0) store_out(outp, isbf, sample, t + 1, y);
  }
}

extern "C" void kernel_launch(void* const* d_in, const int* in_sizes, int n_in,
                              void* d_out, int out_size, void* d_ws, size_t ws_size,
                              hipStream_t stream) {
  P16 wp;
  for (int i = 0; i < 16; ++i) wp.p[i] = d_in[3 + i];
  float* ws = (float*)d_ws;
  hipLaunchKernelGGL(prep_kernel, dim3(80), dim3(256), 0, stream, wp, d_in[1], ws);
  hipLaunchKernelGGL(sde_kernel, dim3(NS / 64), dim3(512), 0, stream, d_in[0], d_in[2],
                     ws, d_out);
}

// Round 4
// 12217.554 us; speedup vs baseline: 10.2737x; 10.2737x over previous
//
#include <hip/hip_runtime.h>
#include <hip/hip_bf16.h>

#define NS 32768
#define NT 512
#define HD 64

// d_ws layout (floats):
//   0      f-net weights PACKED (8900)
//   8900   g-net weights PACKED (8900)
//   17800  dts[511]
//   18311  sqdts[511]
//   18822  flag (1.0 if bf16 inputs else 0.0)
//
// Packed per-net layout (so each 16-unit wave slab is contiguous -> s_load_dwordx16):
//   0     W1p [4 jg][4 k][16 jj]      (orig W1[k][jg*16+jj])
//   256   b1  [64]                    (identity)
//   320   W2p [4 jg][64 k][16 jj]
//   4416  b2  [64]
//   4480  W3p [4 jg][64 k][16 jj]
//   8576  b3  [64]
//   8640  W4  [64 k][4]               (identity: == [4 jg][16 kk][4])
//   8896  b4  [4]
#define WS_NET 8900
#define WS_DTS 17800
#define WS_SQ 18311
#define WS_FLAG 18822

typedef float v2f __attribute__((ext_vector_type(2)));

struct P16 { const void* p[16]; };

__global__ void prep_kernel(P16 wp, const void* timesp, float* ws) {
  unsigned first = ((const unsigned*)timesp)[0];
  bool isbf = (first != 0u);  // times[0]==0.0f -> fp32 dword is 0; bf16 pair is 0x3C240000
  int tid = blockIdx.x * blockDim.x + threadIdx.x;
  int stride = gridDim.x * blockDim.x;
  for (int idx = tid; idx < WS_DTS + (NT - 1); idx += stride) {
    if (idx < WS_DTS) {
      int net = (idx >= WS_NET) ? 1 : 0;
      int r = idx - net * WS_NET;
      int ti, src;
      if (r < 256) {
        int jg = r >> 6, rem = r & 63, k = rem >> 4, jj = rem & 15;
        ti = 0; src = k * 64 + jg * 16 + jj;
      } else if (r < 320) {
        ti = 1; src = r - 256;
      } else if (r < 4416) {
        int rr = r - 320; int jg = rr >> 10, rem = rr & 1023, k = rem >> 4, jj = rem & 15;
        ti = 2; src = k * 64 + jg * 16 + jj;
      } else if (r < 4480) {
        ti = 3; src = r - 4416;
      } else if (r < 8576) {
        int rr = r - 4480; int jg = rr >> 10, rem = rr & 1023, k = rem >> 4, jj = rem & 15;
        ti = 4; src = k * 64 + jg * 16 + jj;
      } else if (r < 8640) {
        ti = 5; src = r - 8576;
      } else if (r < 8896) {
        ti = 6; src = r - 8640;
      } else {
        ti = 7; src = r - 8896;
      }
      ti += net * 8;
      float v = isbf ? __bfloat162float(((const __hip_bfloat16*)wp.p[ti])[src])
                     : ((const float*)wp.p[ti])[src];
      ws[idx] = v;
    } else {
      int t = idx - WS_DTS;
      float t0, t1;
      if (isbf) {
        t0 = __bfloat162float(((const __hip_bfloat16*)timesp)[t]);
        t1 = __bfloat162float(((const __hip_bfloat16*)timesp)[t + 1]);
      } else {
        t0 = ((const float*)timesp)[t];
        t1 = ((const float*)timesp)[t + 1];
      }
      float dt = t1 - t0;
      ws[WS_DTS + t] = dt;
      ws[WS_SQ + t] = sqrtf(dt);
    }
  }
  if (blockIdx.x == 0 && threadIdx.x == 0) ws[WS_FLAG] = isbf ? 1.0f : 0.0f;
}

__device__ __forceinline__ float lipswish(float x) {
  float e = __expf(-x);
  return 0.909f * x * __builtin_amdgcn_rcpf(1.0f + e);
}

__device__ __forceinline__ unsigned short f2bs(float x) {
  return __bfloat16_as_ushort(__float2bfloat16(x));
}

__device__ __forceinline__ void store_out(void* outp, bool isbf, int sample, int t,
                                          const float v[4]) {
  if (isbf) {
    uint2 u;
    u.x = (unsigned)f2bs(v[0]) | ((unsigned)f2bs(v[1]) << 16);
    u.y = (unsigned)f2bs(v[2]) | ((unsigned)f2bs(v[3]) << 16);
    ((uint2*)outp)[(size_t)sample * NT + t] = u;
  } else {
    float4 f = make_float4(v[0], v[1], v[2], v[3]);
    ((float4*)outp)[(size_t)sample * NT + t] = f;
  }
}

// block = 512 threads = 8 waves per 64-sample tile (round-2 structure).
// wave = (net, jgroup): waves 0-3 compute f-net units [16*jg,16*jg+16),
// waves 4-7 the same for g-net. Hidden state exchanged via LDS
// h[net][unit][sample] (stride-1 across lanes -> conflict-free).
// SINGLE-buffered h (32KB) + 1 extra barrier/step: LDS 48KB -> 3 blocks/CU
// = 24 waves/CU = 6 waves/SIMD (vs round-2's 2 blocks/80KB/4 waves).
// Accumulators are v2f with ALL COMPILE-TIME indices (rule #20: runtime
// indexing demotes to scratch — round-3 failure mode) -> v_pk_fma_f32
// halves FMA issue vs round 2. Per-unit accumulation order unchanged ->
// bit-identical numerics to round 2.
// Weight slabs contiguous per wave (packed by prep), readfirstlane-uniform
// base -> s_load_dwordx16 operands, zero VGPR cost.
__global__ __launch_bounds__(512, 6) void sde_kernel(
    const void* __restrict__ y0p, const void* __restrict__ noisep,
    const float* __restrict__ ws, void* __restrict__ outp) {
  const int tid = threadIdx.x;
  const int lane = tid & 63;
  const int uwv = __builtin_amdgcn_readfirstlane(tid >> 6);  // 0..7 wave-uniform
  const int unet = uwv >> 2;  // 0 = f-net, 1 = g-net
  const int ujg = uwv & 3;    // which 16-unit group
  const int j0 = ujg * 16;
  const int sample = blockIdx.x * 64 + lane;
  const bool isbf = (ws[WS_FLAG] != 0.0f);

  const float* Wb = ws + unet * WS_NET;
  const float* W1p = Wb + ujg * 64;          // [4][16]
  const float* b1p = Wb + 256 + ujg * 16;    // [16]
  const float* W2p = Wb + 320 + ujg * 1024;  // [64][16]
  const float* b2p = Wb + 4416 + ujg * 16;
  const float* W3p = Wb + 4480 + ujg * 1024;
  const float* b3p = Wb + 8576 + ujg * 16;
  const float* W4p = Wb + 8640 + ujg * 64;   // [16][4]
  const float* b4 = Wb + 8896;
  const float* dts = ws + WS_DTS;
  const float* sqdts = ws + WS_SQ;

  __shared__ float h[2][HD][64];       // [net][unit][sample] = 32KB, single-buffered
  __shared__ float exch[2][8][4][64];  // [slot][wave][d][sample] = 16KB

  float y[4];
  if (isbf) {
    const __hip_bfloat16* y0 = (const __hip_bfloat16*)y0p;
#pragma unroll
    for (int d = 0; d < 4; ++d) y[d] = __bfloat162float(y0[sample * 4 + d]);
  } else {
    const float* y0 = (const float*)y0p;
#pragma unroll
    for (int d = 0; d < 4; ++d) y[d] = y0[sample * 4 + d];
  }

  if (uwv == 0) store_out(outp, isbf, sample, 0, y);

  for (int t = 0; t < NT - 1; ++t) {
    // prefetch this step's noise early; used only at the end of the step
    float dw[4];
    if (isbf) {
      uint2 nz = ((const uint2*)noisep)[(size_t)t * NS + sample];
      dw[0] = __uint_as_float((nz.x & 0xffffu) << 16);
      dw[1] = __uint_as_float(nz.x & 0xffff0000u);
      dw[2] = __uint_as_float((nz.y & 0xffffu) << 16);
      dw[3] = __uint_as_float(nz.y & 0xffff0000u);
    } else {
      float4 nz = ((const float4*)noisep)[(size_t)t * NS + sample];
      dw[0] = nz.x; dw[1] = nz.y; dw[2] = nz.z; dw[3] = nz.w;
    }

    v2f a[8];
    // L1: [4] -> 16 units of this wave (v2f pairs, static indices only)
#pragma unroll
    for (int c = 0; c < 8; ++c) a[c] = *(const v2f*)(b1p + 2 * c);
#pragma unroll
    for (int k = 0; k < 4; ++k) {
      v2f yk = {y[k], y[k]};
      const v2f* wr = (const v2f*)(W1p + k * 16);
#pragma unroll
      for (int c = 0; c < 8; ++c) a[c] = __builtin_elementwise_fma(yk, wr[c], a[c]);
    }
#pragma unroll
    for (int c = 0; c < 8; ++c) {
      h[unet][j0 + 2 * c][lane] = lipswish(a[c][0]);
      h[unet][j0 + 2 * c + 1][lane] = lipswish(a[c][1]);
    }
    __syncthreads();  // A: h1 ready

    // L2: all 64 of this net -> 16 units of this wave
#pragma unroll
    for (int c = 0; c < 8; ++c) a[c] = *(const v2f*)(b2p + 2 * c);
#pragma unroll 4
    for (int k = 0; k < HD; ++k) {
      float hk = h[unet][k][lane];
      v2f hk2 = {hk, hk};
      const v2f* wr = (const v2f*)(W2p + k * 16);
#pragma unroll
      for (int c = 0; c < 8; ++c) a[c] = __builtin_elementwise_fma(hk2, wr[c], a[c]);
    }
    __syncthreads();  // B: h1 fully consumed by all waves, safe to overwrite
#pragma unroll
    for (int c = 0; c < 8; ++c) {
      h[unet][j0 + 2 * c][lane] = lipswish(a[c][0]);
      h[unet][j0 + 2 * c + 1][lane] = lipswish(a[c][1]);
    }
    __syncthreads();  // C: h2 ready

    // L3: all 64 of this net -> 16 units, pre-acts kept in registers
#pragma unroll
    for (int c = 0; c < 8; ++c) a[c] = *(const v2f*)(b3p + 2 * c);
#pragma unroll 4
    for (int k = 0; k < HD; ++k) {
      float hk = h[unet][k][lane];
      v2f hk2 = {hk, hk};
      const v2f* wr = (const v2f*)(W3p + k * 16);
#pragma unroll
      for (int c = 0; c < 8; ++c) a[c] = __builtin_elementwise_fma(hk2, wr[c], a[c]);
    }

    // L4 partial: this wave's 16 h3 values -> partial o[4] (k-split)
    v2f oA, oB;
    if (ujg == 0) {
      oA = *(const v2f*)(b4 + 0);
      oB = *(const v2f*)(b4 + 2);
    } else {
      oA = (v2f){0.f, 0.f};
      oB = (v2f){0.f, 0.f};
    }
#pragma unroll
    for (int kk = 0; kk < 16; ++kk) {
      float h3 = lipswish(a[kk >> 1][kk & 1]);  // kk is unrolled -> static index
      v2f h2 = {h3, h3};
      const v2f* wr = (const v2f*)(W4p + kk * 4);
      oA = __builtin_elementwise_fma(h2, wr[0], oA);
      oB = __builtin_elementwise_fma(h2, wr[1], oB);
    }

    const int slot = t & 1;  // double-buffered exchange
    exch[slot][uwv][0][lane] = oA[0];
    exch[slot][uwv][1][lane] = oA[1];
    exch[slot][uwv][2][lane] = oB[0];
    exch[slot][uwv][3][lane] = oB[1];
    __syncthreads();  // D: exch ready AND h2 consumed (all L3 reads precede this)

    // reduce partials + Euler-Maruyama update (redundant in every wave)
    const float dt = dts[t];
    const float sq = sqdts[t];
#pragma unroll
    for (int d = 0; d < 4; ++d) {
      float fsum = (exch[slot][0][d][lane] + exch[slot][1][d][lane]) +
                   (exch[slot][2][d][lane] + exch[slot][3][d][lane]);
      float gsum = (exch[slot][4][d][lane] + exch[slot][5][d][lane]) +
                   (exch[slot][6][d][lane] + exch[slot][7][d][lane]);
      float drift = fminf(fmaxf(fsum, -100.0f), 100.0f);
      float sp = fmaxf(gsum, 0.0f) + log1pf(__expf(-fabsf(gsum)));  // stable softplus
      float diff = fmaxf(sp, 1e-4f);
      y[d] = y[d] + drift * dt + diff * sq * dw[d];
    }

    if (uwv == 0) store_out(outp, isbf, sample, t + 1, y);
  }
}

extern "C" void kernel_launch(void* const* d_in, const int* in_sizes, int n_in,
                              void* d_out, int out_size, void* d_ws, size_t ws_size,
                              hipStream_t stream) {
  P16 wp;
  for (int i = 0; i < 16; ++i) wp.p[i] = d_in[3 + i];
  float* ws = (float*)d_ws;
  hipLaunchKernelGGL(prep_kernel, dim3(80), dim3(256), 0, stream, wp, d_in[1], ws);
  hipLaunchKernelGGL(sde_kernel, dim3(NS / 64), dim3(512), 0, stream, d_in[0], d_in[2],
                     ws, d_out);
}